// Round 1
// 444.840 us; speedup vs baseline: 1.1000x; 1.1000x over previous
//
#include <hip/hip_runtime.h>
#include <hip/hip_bf16.h>
#include <stdint.h>

// BcosGCNLayer: out[n,o] = lin * |lin| / (R_n * C_o),  lin = z @ W^T
//   R_n = max(||z_n||, eps), C_o = max(||w_o||, eps), eps = 1e-12
// z: [M,512] fp32, W: [512,512] fp32, out: [M,512] fp32.
//
// V2 structure: block = 64 rows x 512 cols (ALL cols), 512 threads = 8 waves,
// each wave 64x64. z staged to LDS bf16 ONCE per block (fetch-optimal, no
// inter-block z reuse required); B fragments read directly from L2-resident
// bf16 W (512 KB, hot on every XCD). K-loop has NO barriers -> no vmcnt(0)
// drains, loads pipeline freely across MFMAs.

constexpr int KDIM = 512;
constexpr int NDIM = 512;

typedef __attribute__((ext_vector_type(8))) short bf16x8;   // MFMA A/B frag (4 VGPR)
typedef __attribute__((ext_vector_type(4))) float f32x4;    // MFMA C/D frag

__device__ __forceinline__ uint32_t pk_bf16(float a, float b) {
  __hip_bfloat162 h = __float22bfloat162_rn(make_float2(a, b));
  union { __hip_bfloat162 h2; uint32_t u; } c;
  c.h2 = h;
  return c.u;  // low 16 = a, high 16 = b
}

// ---------- prep: W fp32 -> bf16 (row-major), and 1/max(||w_o||,eps) ----------
__global__ __launch_bounds__(128) void prep_w(const float* __restrict__ w,
                                              unsigned short* __restrict__ wb,
                                              float* __restrict__ cninv) {
  const int row = blockIdx.x;   // 0..511
  const int t   = threadIdx.x;  // 0..127, 4 floats each
  const float* gp = w + (size_t)row * KDIM + t * 4;
  f32x4 v = *(const f32x4*)gp;
  float s = v.x * v.x + v.y * v.y + v.z * v.z + v.w * v.w;

  uint2 p;
  p.x = pk_bf16(v.x, v.y);
  p.y = pk_bf16(v.z, v.w);
  *(uint2*)(wb + (size_t)row * KDIM + t * 4) = p;

  #pragma unroll
  for (int off = 32; off > 0; off >>= 1) s += __shfl_down(s, off, 64);
  __shared__ float red[2];
  if ((t & 63) == 0) red[t >> 6] = s;
  __syncthreads();
  if (t == 0) cninv[row] = 1.0f / fmaxf(sqrtf(red[0] + red[1]), 1e-12f);
}

// ---------- main fused GEMM ----------
// grid.x = ceil(M/64); 512 threads; wave w owns cols [64w, 64w+64).
__global__ __launch_bounds__(512, 4) void gemm_bcos(const float* __restrict__ z,
                                                    const unsigned short* __restrict__ wb,
                                                    const float* __restrict__ cninv,
                                                    float* __restrict__ out, int M) {
  // A tile: 64 rows x 512 k, bf16, row stride 1024 B, XOR-swizzled:
  //   stored byte = row*1024 + (col_byte ^ ((row&7)<<4))
  // -> ds_read_b128 a-frags hit 8 distinct 16B slots per 8 rows (<=2-way, free).
  __shared__ unsigned short As[64 * 512];  // 64 KiB
  __shared__ float rowsq[64];
  __shared__ float rinv[64];

  const int t    = threadIdx.x;
  const int w    = t >> 6;      // wave 0..7
  const int lane = t & 63;
  const int lrow = lane & 15;   // A-frag m / B-frag n / C col
  const int quad = lane >> 4;   // k-chunk select; C row base = quad*4
  const int mb   = blockIdx.x;
  const int wn   = w * 64;      // this wave's col base

  // ---- stage A: wave w handles rows 8w..8w+7; fp32 loads -> sumsq -> bf16 LDS ----
  #pragma unroll
  for (int rr = 0; rr < 8; ++rr) {
    const int rl = w * 8 + rr;          // local row; rl&7 == rr (8w = 0 mod 8)
    int rg = mb * 64 + rl;
    if (rg >= M) rg = M - 1;            // tail clamp (stores are guarded)
    const float* zp = z + (size_t)rg * KDIM;
    float s = 0.0f;
    #pragma unroll
    for (int j = 0; j < 2; ++j) {
      f32x4 v = __builtin_nontemporal_load((const f32x4*)(zp + j * 256 + lane * 4));
      s += v.x * v.x + v.y * v.y + v.z * v.z + v.w * v.w;
      uint2 p;
      p.x = pk_bf16(v.x, v.y);
      p.y = pk_bf16(v.z, v.w);
      const int cb = (j * 512 + lane * 8) ^ (rr << 4);  // swizzled col byte
      *(uint2*)((char*)As + rl * 1024 + cb) = p;
    }
    #pragma unroll
    for (int off = 32; off > 0; off >>= 1) s += __shfl_down(s, off, 64);
    if (lane == 0) rowsq[rl] = s;
  }
  __syncthreads();
  if (t < 64) rinv[t] = 1.0f / fmaxf(sqrtf(rowsq[t]), 1e-12f);
  __syncthreads();

  // ---- K loop: 16 k-steps of 32, NO barriers. B streamed from L2-hot wb. ----
  f32x4 acc[4][4];
  #pragma unroll
  for (int i = 0; i < 4; ++i)
    #pragma unroll
    for (int j = 0; j < 4; ++j) acc[i][j] = (f32x4)0.0f;

  const int qs = (quad * 16) ^ ((lrow & 7) << 4);  // swizzle bits 4..6 for a-reads
  const unsigned short* wbp = wb + (size_t)(wn + lrow) * KDIM + quad * 8;

  #pragma unroll 2
  for (int ks = 0; ks < 16; ++ks) {
    bf16x8 a[4], b[4];
    #pragma unroll
    for (int nt = 0; nt < 4; ++nt)
      b[nt] = *(const bf16x8*)(wbp + nt * 16 * KDIM + ks * 32);
    #pragma unroll
    for (int mt = 0; mt < 4; ++mt)
      a[mt] = *(const bf16x8*)((const char*)As + ((mt * 16 + lrow) << 10) + ((ks * 64) ^ qs));
    #pragma unroll
    for (int mt = 0; mt < 4; ++mt)
      #pragma unroll
      for (int nt = 0; nt < 4; ++nt)
        acc[mt][nt] = __builtin_amdgcn_mfma_f32_16x16x32_bf16(a[mt], b[nt], acc[mt][nt], 0, 0, 0);
  }

  // ---- epilogue: out = v*|v| * Rinv * Cinv (C/D: col=lane&15, row=quad*4+reg) ----
  #pragma unroll
  for (int nt = 0; nt < 4; ++nt) {
    const int colg = wn + nt * 16 + lrow;
    const float cv = cninv[colg];
    #pragma unroll
    for (int mt = 0; mt < 4; ++mt) {
      const int rl = mt * 16 + quad * 4;
      #pragma unroll
      for (int i = 0; i < 4; ++i) {
        const int rowg = mb * 64 + rl + i;
        if (rowg < M) {
          const float v = acc[mt][nt][i];
          __builtin_nontemporal_store(v * fabsf(v) * rinv[rl + i] * cv,
                                      &out[(size_t)rowg * NDIM + colg]);
        }
      }
    }
  }
}

extern "C" void kernel_launch(void* const* d_in, const int* in_sizes, int n_in,
                              void* d_out, int out_size, void* d_ws, size_t ws_size,
                              hipStream_t stream) {
  const float* z = (const float*)d_in[0];
  const float* w = (const float*)d_in[1];
  float* out = (float*)d_out;
  const int M = in_sizes[0] / KDIM;  // 100000

  unsigned short* wb = (unsigned short*)d_ws;                     // 512*512 bf16 = 512 KB
  float* cninv = (float*)((char*)d_ws + (size_t)NDIM * KDIM * 2); // 512 fp32

  prep_w<<<dim3(NDIM), dim3(128), 0, stream>>>(w, wb, cninv);

  dim3 grid((M + 63) / 64);  // 1563 blocks, 64 rows each, all 512 cols
  gemm_bcos<<<grid, dim3(512), 0, stream>>>(z, wb, cninv, out, M);
}

// Round 2
// 422.695 us; speedup vs baseline: 1.1576x; 1.0524x over previous
//
#include <hip/hip_runtime.h>
#include <hip/hip_bf16.h>
#include <stdint.h>

// BcosGCNLayer: out[n,o] = lin * |lin| / (R_n * C_o),  lin = z @ W^T
//   R_n = max(||z_n||, eps), C_o = max(||w_o||, eps), eps = 1e-12
// z: [M,512] fp32, W: [512,512] fp32, out: [M,512] fp32.
//
// V3: block = 64 rows x 512 cols, 512 threads = 8 waves (wave w: cols 64w..64w+63).
// z staged to LDS bf16 once (fused row norms). B chunks (512 cols x 32 k) DMA'd
// via global_load_lds into a double buffer with counted vmcnt(4) waits (never 0
// mid-loop) + raw s_barriers -> B-load latency spans 2 full chunks of MFMA.
// W pre-transposed into [chunk][k8][col] 16B-granule layout so the linear DMA
// dest gives conflict-free ds_read_b128 b-frags.

constexpr int KDIM = 512;
constexpr int NDIM = 512;

typedef __attribute__((ext_vector_type(8))) short bf16x8;   // MFMA A/B frag (4 VGPR)
typedef __attribute__((ext_vector_type(4))) float f32x4;    // MFMA C/D frag

__device__ __forceinline__ uint32_t pk_bf16(float a, float b) {
  __hip_bfloat162 h = __float22bfloat162_rn(make_float2(a, b));
  union { __hip_bfloat162 h2; uint32_t u; } c;
  c.h2 = h;
  return c.u;  // low 16 = a, high 16 = b
}

__device__ __forceinline__ void gload_lds16(const void* g, void* lds) {
  // async global->LDS DMA, 16B/lane; LDS dest = wave-uniform base + lane*16.
  __builtin_amdgcn_global_load_lds(
      (const __attribute__((address_space(1))) uint32_t*)(uintptr_t)g,
      (__attribute__((address_space(3))) uint32_t*)(uintptr_t)lds,
      16, 0, 0);
}

// ---------- prep: W fp32 -> bf16 transposed-granule layout + 1/max(||w_o||,eps) ----
// wbt granule g of chunk c (granule = 8 bf16 = 16 B):  g = k8*512 + col, k8=0..3
//   wbt[(c*2048 + g)*8 .. +8] = W_bf16[col][c*32 + k8*8 .. +8]
__global__ __launch_bounds__(128) void prep_w(const float* __restrict__ w,
                                              unsigned short* __restrict__ wbt,
                                              float* __restrict__ cninv) {
  const int row = blockIdx.x;   // 0..511 (the B "col")
  const int t   = threadIdx.x;  // 0..127, 4 floats each
  const int k0  = t * 4;
  f32x4 v = *(const f32x4*)(w + (size_t)row * KDIM + k0);
  float s = v.x * v.x + v.y * v.y + v.z * v.z + v.w * v.w;

  uint2 p;
  p.x = pk_bf16(v.x, v.y);
  p.y = pk_bf16(v.z, v.w);
  const int c  = k0 >> 5;
  const int k8 = (k0 >> 3) & 3;
  *(uint2*)(wbt + ((size_t)c * 2048 + k8 * 512 + row) * 8 + (k0 & 7)) = p;

  #pragma unroll
  for (int off = 32; off > 0; off >>= 1) s += __shfl_down(s, off, 64);
  __shared__ float red[2];
  if ((t & 63) == 0) red[t >> 6] = s;
  __syncthreads();
  if (t == 0) cninv[row] = 1.0f / fmaxf(sqrtf(red[0] + red[1]), 1e-12f);
}

// ---------- main fused GEMM ----------
__global__ __launch_bounds__(512, 2) void gemm_bcos(const float* __restrict__ z,
                                                    const unsigned short* __restrict__ wbt,
                                                    const float* __restrict__ cninv,
                                                    float* __restrict__ out, int M) {
  __shared__ unsigned short As[64 * 512];      // 64 KiB, XOR-swizzled rows
  __shared__ unsigned short Bs[2][2048 * 8];   // 2 x 32 KiB [k8][col] granules
  __shared__ float rowsq[64];
  __shared__ float rinv_s[64];

  const int t    = threadIdx.x;
  const int w    = t >> 6;
  const int lane = t & 63;
  const int lrow = lane & 15;   // frag row/col index
  const int quad = lane >> 4;   // k-chunk select; C row base = quad*4
  const int mb   = blockIdx.x;
  const int wn   = w * 64;

  // ---- issue DMA for B chunks 0 and 1 immediately (hidden under z staging) ----
  #pragma unroll
  for (int i = 0; i < 4; ++i)
    gload_lds16(wbt + (size_t)(t + 512 * i) * 8, &Bs[0][(t + 512 * i) * 8]);
  #pragma unroll
  for (int i = 0; i < 4; ++i)
    gload_lds16(wbt + (size_t)(2048 + t + 512 * i) * 8, &Bs[1][(t + 512 * i) * 8]);

  // ---- stage A: wave w rows 8w..8w+7; fp32 -> sumsq -> bf16 -> swizzled LDS ----
  #pragma unroll
  for (int rr = 0; rr < 8; ++rr) {
    const int rl = w * 8 + rr;          // rl&7 == rr
    int rg = mb * 64 + rl;
    if (rg >= M) rg = M - 1;            // tail clamp (stores are guarded)
    const float* zp = z + (size_t)rg * KDIM;
    float s = 0.0f;
    #pragma unroll
    for (int j = 0; j < 2; ++j) {
      f32x4 v = *(const f32x4*)(zp + j * 256 + lane * 4);
      s += v.x * v.x + v.y * v.y + v.z * v.z + v.w * v.w;
      uint2 p;
      p.x = pk_bf16(v.x, v.y);
      p.y = pk_bf16(v.z, v.w);
      const int cb = (j * 512 + lane * 8) ^ (rr << 4);  // swizzled col byte
      *(uint2*)((char*)As + rl * 1024 + cb) = p;
    }
    #pragma unroll
    for (int off = 32; off > 0; off >>= 1) s += __shfl_down(s, off, 64);
    if (lane == 0) rowsq[rl] = s;
  }
  __syncthreads();
  if (t < 64) rinv_s[t] = 1.0f / fmaxf(sqrtf(rowsq[t]), 1e-12f);
  __syncthreads();   // As + rinv ready; drains staging loads (DMA 0/1 long done)

  // ---- K loop: 16 chunks of BK=32, counted-vmcnt double-buffered B ----
  f32x4 acc[4][4];
  #pragma unroll
  for (int i = 0; i < 4; ++i)
    #pragma unroll
    for (int j = 0; j < 4; ++j) acc[i][j] = (f32x4)0.0f;

  const int qs = (quad * 16) ^ ((lrow & 7) << 4);  // A-read swizzle bits 4..6

  bf16x8 a[2][4];
  #pragma unroll
  for (int mt = 0; mt < 4; ++mt)
    a[0][mt] = *(const bf16x8*)((const char*)As + ((mt * 16 + lrow) << 10) + (0 ^ qs));

  #pragma unroll
  for (int c = 0; c < 16; ++c) {
    if (c < 15) asm volatile("s_waitcnt vmcnt(4)" ::: "memory");
    else        asm volatile("s_waitcnt vmcnt(0)" ::: "memory");
    __builtin_amdgcn_s_barrier();        // A: Bs[c&1] filled for all waves
    asm volatile("" ::: "memory");       // fence: no ds_read hoists above barrier

    bf16x8 b[4];
    #pragma unroll
    for (int nt = 0; nt < 4; ++nt)
      b[nt] = *(const bf16x8*)&Bs[c & 1][(quad * 512 + wn + nt * 16 + lrow) * 8];
    if (c < 15) {
      #pragma unroll
      for (int mt = 0; mt < 4; ++mt)
        a[(c + 1) & 1][mt] = *(const bf16x8*)((const char*)As +
            ((mt * 16 + lrow) << 10) + (((c + 1) * 64) ^ qs));
    }

    __builtin_amdgcn_s_setprio(1);
    #pragma unroll
    for (int mt = 0; mt < 4; ++mt)
      #pragma unroll
      for (int nt = 0; nt < 4; ++nt)
        acc[mt][nt] = __builtin_amdgcn_mfma_f32_16x16x32_bf16(a[c & 1][mt], b[nt], acc[mt][nt], 0, 0, 0);
    __builtin_amdgcn_s_setprio(0);

    asm volatile("" ::: "memory");       // fence: ds_reads issued before barrier B
    __builtin_amdgcn_s_barrier();        // B: all waves done reading Bs[c&1]
    if (c + 2 < 16) {
      #pragma unroll
      for (int i = 0; i < 4; ++i)
        gload_lds16(wbt + ((size_t)(c + 2) * 2048 + t + 512 * i) * 8,
                    &Bs[c & 1][(t + 512 * i) * 8]);
    }
  }

  // ---- epilogue: out = v*|v| * Rinv * Cinv (C/D: col=lane&15, row=quad*4+reg) ----
  #pragma unroll
  for (int nt = 0; nt < 4; ++nt) {
    const int colg = wn + nt * 16 + lrow;
    const float cv = cninv[colg];
    #pragma unroll
    for (int mt = 0; mt < 4; ++mt) {
      const int rl = mt * 16 + quad * 4;
      #pragma unroll
      for (int i = 0; i < 4; ++i) {
        const int rowg = mb * 64 + rl + i;
        if (rowg < M) {
          const float v = acc[mt][nt][i];
          __builtin_nontemporal_store(v * fabsf(v) * rinv_s[rl + i] * cv,
                                      &out[(size_t)rowg * NDIM + colg]);
        }
      }
    }
  }
}

extern "C" void kernel_launch(void* const* d_in, const int* in_sizes, int n_in,
                              void* d_out, int out_size, void* d_ws, size_t ws_size,
                              hipStream_t stream) {
  const float* z = (const float*)d_in[0];
  const float* w = (const float*)d_in[1];
  float* out = (float*)d_out;
  const int M = in_sizes[0] / KDIM;  // 100000

  unsigned short* wbt = (unsigned short*)d_ws;                    // 512 KB bf16, granule layout
  float* cninv = (float*)((char*)d_ws + (size_t)NDIM * KDIM * 2); // 512 fp32

  prep_w<<<dim3(NDIM), dim3(128), 0, stream>>>(w, wbt, cninv);

  dim3 grid((M + 63) / 64);  // 1563 blocks, 64 rows each, all 512 cols
  gemm_bcos<<<grid, dim3(512), 0, stream>>>(z, wbt, cninv, out, M);
}